// Round 1
// baseline (3293.831 us; speedup 1.0000x reference)
//
#include <hip/hip_runtime.h>

#define D 256
#define DV 64   // D/4 float4s per row

// ---------------- CSR build ----------------

__global__ void k_hist(const int* __restrict__ dst, int* __restrict__ deg, int E) {
    int e = blockIdx.x * blockDim.x + threadIdx.x;
    if (e < E) atomicAdd(&deg[dst[e]], 1);
}

__global__ void k_blocksum(const int* __restrict__ deg, int* __restrict__ bsum, int n) {
    __shared__ int s[256];
    int b = blockIdx.x, t = threadIdx.x;
    int base = b * 1024;
    int v = 0;
    for (int i = t; i < 1024; i += 256) {
        int idx = base + i;
        if (idx < n) v += deg[idx];
    }
    s[t] = v;
    __syncthreads();
    for (int off = 128; off > 0; off >>= 1) {
        if (t < off) s[t] += s[t + off];
        __syncthreads();
    }
    if (t == 0) bsum[b] = s[0];
}

__global__ void k_scanbsum(int* bsum, int nb, int* offs, int n, int total) {
    if (threadIdx.x == 0 && blockIdx.x == 0) {
        int run = 0;
        for (int i = 0; i < nb; i++) { int v = bsum[i]; bsum[i] = run; run += v; }
        offs[n] = total;
    }
}

__global__ void k_scanwrite(const int* __restrict__ deg, const int* __restrict__ bsum,
                            int* __restrict__ offs, int* __restrict__ cursor, int n) {
    __shared__ int s[256];
    int b = blockIdx.x, t = threadIdx.x;
    int base = b * 1024 + t * 4;
    int v[4];
    int sum = 0;
    #pragma unroll
    for (int j = 0; j < 4; j++) {
        int idx = base + j;
        v[j] = (idx < n) ? deg[idx] : 0;
        sum += v[j];
    }
    s[t] = sum;
    __syncthreads();
    for (int off = 1; off < 256; off <<= 1) {
        int xv = (t >= off) ? s[t - off] : 0;
        __syncthreads();
        s[t] += xv;
        __syncthreads();
    }
    int excl = s[t] - sum + bsum[b];   // exclusive within grid
    #pragma unroll
    for (int j = 0; j < 4; j++) {
        int idx = base + j;
        if (idx < n) { offs[idx] = excl; cursor[idx] = excl; excl += v[j]; }
    }
}

__global__ void k_scatter(const int* __restrict__ src, const int* __restrict__ dst,
                          int* __restrict__ cursor, int* __restrict__ srcs, int E) {
    int e = blockIdx.x * blockDim.x + threadIdx.x;
    if (e < E) {
        int d = dst[e];
        int p = atomicAdd(&cursor[d], 1);
        srcs[p] = src[e];
    }
}

// ---------------- embedding gather ----------------

__global__ void k_gather(const int* __restrict__ x, const float* __restrict__ emb,
                         float* __restrict__ h, int N) {
    int idx = blockIdx.x * blockDim.x + threadIdx.x;
    if (idx >= N * DV) return;
    int node = idx >> 6, c = idx & 63;
    int s = x[node];
    ((float4*)h)[(size_t)node * DV + c] = ((const float4*)emb)[(size_t)s * DV + c];
}

// ---------------- mean aggregation (wave per node) ----------------

__global__ void k_agg(const float* __restrict__ h, const int* __restrict__ offs,
                      const int* __restrict__ srcs, float* __restrict__ out, int N) {
    int wid = (blockIdx.x * blockDim.x + threadIdx.x) >> 6;
    int lane = threadIdx.x & 63;
    if (wid >= N) return;
    int beg = offs[wid], end = offs[wid + 1];
    const float4* hv = (const float4*)h;
    float4 acc; acc.x = 0.f; acc.y = 0.f; acc.z = 0.f; acc.w = 0.f;
    int e = beg;
    for (; e + 3 < end; e += 4) {
        int j0 = srcs[e], j1 = srcs[e + 1], j2 = srcs[e + 2], j3 = srcs[e + 3];
        float4 v0 = hv[(size_t)j0 * DV + lane];
        float4 v1 = hv[(size_t)j1 * DV + lane];
        float4 v2 = hv[(size_t)j2 * DV + lane];
        float4 v3 = hv[(size_t)j3 * DV + lane];
        acc.x += (v0.x + v1.x) + (v2.x + v3.x);
        acc.y += (v0.y + v1.y) + (v2.y + v3.y);
        acc.z += (v0.z + v1.z) + (v2.z + v3.z);
        acc.w += (v0.w + v1.w) + (v2.w + v3.w);
    }
    for (; e < end; ++e) {
        int j = srcs[e];
        float4 v = hv[(size_t)j * DV + lane];
        acc.x += v.x; acc.y += v.y; acc.z += v.z; acc.w += v.w;
    }
    int dg = end - beg;
    float inv = 1.0f / (float)(dg < 1 ? 1 : dg);
    float4 r; r.x = acc.x * inv; r.y = acc.y * inv; r.z = acc.z * inv; r.w = acc.w * inv;
    ((float4*)out)[(size_t)wid * DV + lane] = r;
}

// ---------------- fp32 GEMM: out[M,256] = A[M,256] @ W[256,256]^T (+bias)(+=)(prelu) ----------------
// BM=64, BN=256 (full width -> blocks own rows exclusively; in-place safe), BK=32, 512 thr.

__global__ __launch_bounds__(512)
void k_gemm(const float* __restrict__ A, const float* __restrict__ W,
            const float* __restrict__ bias, const float* __restrict__ prelu_a,
            int accum, float* __restrict__ out, int M) {
    __shared__ float As[32][64];
    __shared__ float Bs[32][256];
    int tid = threadIdx.x;
    int tx = tid & 31;       // col group 0..31
    int ty = tid >> 5;       // row group 0..15
    int m0 = blockIdx.x * 64;

    float acc[4][8];
    #pragma unroll
    for (int i = 0; i < 4; i++)
        #pragma unroll
        for (int j = 0; j < 8; j++) acc[i][j] = 0.f;

    int arow = tid >> 3;     // 0..63
    int ac4  = tid & 7;      // 0..7 (float4 index along K chunk)
    int an = m0 + arow;

    for (int kt = 0; kt < 8; ++kt) {
        int k0 = kt * 32;
        float4 aReg; aReg.x = 0.f; aReg.y = 0.f; aReg.z = 0.f; aReg.w = 0.f;
        if (an < M) aReg = *(const float4*)&A[(size_t)an * D + k0 + ac4 * 4];
        float4 bReg[4];
        #pragma unroll
        for (int q = 0; q < 4; q++) {
            int idx = tid + q * 512;
            int bn = idx >> 3, bc4 = idx & 7;
            bReg[q] = *(const float4*)&W[(size_t)bn * D + k0 + bc4 * 4];
        }
        __syncthreads();
        As[ac4 * 4 + 0][arow] = aReg.x;
        As[ac4 * 4 + 1][arow] = aReg.y;
        As[ac4 * 4 + 2][arow] = aReg.z;
        As[ac4 * 4 + 3][arow] = aReg.w;
        #pragma unroll
        for (int q = 0; q < 4; q++) {
            int idx = tid + q * 512;
            int bn = idx >> 3, bc4 = idx & 7;
            Bs[bc4 * 4 + 0][bn] = bReg[q].x;
            Bs[bc4 * 4 + 1][bn] = bReg[q].y;
            Bs[bc4 * 4 + 2][bn] = bReg[q].z;
            Bs[bc4 * 4 + 3][bn] = bReg[q].w;
        }
        __syncthreads();
        #pragma unroll
        for (int k = 0; k < 32; k++) {
            float4 a4 = *(const float4*)&As[k][ty * 4];
            float4 b0 = *(const float4*)&Bs[k][tx * 4];
            float4 b1 = *(const float4*)&Bs[k][128 + tx * 4];
            float av[4] = {a4.x, a4.y, a4.z, a4.w};
            float bv[8] = {b0.x, b0.y, b0.z, b0.w, b1.x, b1.y, b1.z, b1.w};
            #pragma unroll
            for (int i = 0; i < 4; i++)
                #pragma unroll
                for (int j = 0; j < 8; j++)
                    acc[i][j] += av[i] * bv[j];
        }
    }
    __syncthreads();   // all global A reads done before any write (in-place safety)

    float ap = 0.f;
    if (prelu_a) ap = *prelu_a;
    float4 bb0, bb1;
    bb0.x = bb0.y = bb0.z = bb0.w = 0.f;
    bb1.x = bb1.y = bb1.z = bb1.w = 0.f;
    if (bias) {
        bb0 = *(const float4*)&bias[tx * 4];
        bb1 = *(const float4*)&bias[128 + tx * 4];
    }
    #pragma unroll
    for (int i = 0; i < 4; i++) {
        int row = m0 + ty * 4 + i;
        if (row >= M) continue;
        float o[8];
        #pragma unroll
        for (int j = 0; j < 8; j++) o[j] = acc[i][j];
        if (bias) {
            o[0] += bb0.x; o[1] += bb0.y; o[2] += bb0.z; o[3] += bb0.w;
            o[4] += bb1.x; o[5] += bb1.y; o[6] += bb1.z; o[7] += bb1.w;
        }
        float* op = &out[(size_t)row * D];
        if (accum) {
            float4 e0 = *(const float4*)&op[tx * 4];
            float4 e1 = *(const float4*)&op[128 + tx * 4];
            o[0] += e0.x; o[1] += e0.y; o[2] += e0.z; o[3] += e0.w;
            o[4] += e1.x; o[5] += e1.y; o[6] += e1.z; o[7] += e1.w;
        }
        if (prelu_a) {
            #pragma unroll
            for (int j = 0; j < 8; j++) o[j] = (o[j] >= 0.f) ? o[j] : ap * o[j];
        }
        float4 s0, s1;
        s0.x = o[0]; s0.y = o[1]; s0.z = o[2]; s0.w = o[3];
        s1.x = o[4]; s1.y = o[5]; s1.z = o[6]; s1.w = o[7];
        *(float4*)&op[tx * 4] = s0;
        *(float4*)&op[128 + tx * 4] = s1;
    }
}

// ---------------- launcher ----------------

extern "C" void kernel_launch(void* const* d_in, const int* in_sizes, int n_in,
                              void* d_out, int out_size, void* d_ws, size_t ws_size,
                              hipStream_t stream) {
    const int*   x    = (const int*)d_in[0];
    const int*   ei   = (const int*)d_in[1];
    // d_in[2] = edge_weight (unused by reference)
    const float* emb  = (const float*)d_in[3];
    const float* Wl[3] = {(const float*)d_in[4],  (const float*)d_in[8],  (const float*)d_in[12]};
    const float* bl[3] = {(const float*)d_in[5],  (const float*)d_in[9],  (const float*)d_in[13]};
    const float* Wr[3] = {(const float*)d_in[6],  (const float*)d_in[10], (const float*)d_in[14]};
    const float* pa[3] = {(const float*)d_in[7],  (const float*)d_in[11], (const float*)d_in[15]};
    const float* Wout = (const float*)d_in[16];
    const float* bout = (const float*)d_in[17];

    int N = in_sizes[0];
    int E = in_sizes[1] / 2;
    const int* src = ei;
    const int* dst = ei + E;

    char* ws = (char*)d_ws;
    size_t off = 0;
    auto walloc = [&](size_t bytes) -> void* {
        void* p = ws + off;
        off += (bytes + 255) & ~(size_t)255;
        return p;
    };
    float* A     = (float*)walloc((size_t)N * D * sizeof(float));
    float* C     = (float*)walloc((size_t)N * D * sizeof(float));
    int*   deg   = (int*)walloc((size_t)N * sizeof(int));
    int*   offs  = (int*)walloc((size_t)(N + 1) * sizeof(int));
    int*   cursor= (int*)walloc((size_t)N * sizeof(int));
    int*   bsum  = (int*)walloc(4096);
    int*   srcs  = (int*)walloc((size_t)E * sizeof(int));
    float* B     = (float*)d_out;   // ping-pong through the output buffer

    // --- CSR build ---
    hipMemsetAsync(deg, 0, (size_t)N * sizeof(int), stream);
    int eb = (E + 255) / 256;
    int nb = (N + 1023) / 1024;
    k_hist<<<eb, 256, 0, stream>>>(dst, deg, E);
    k_blocksum<<<nb, 256, 0, stream>>>(deg, bsum, N);
    k_scanbsum<<<1, 64, 0, stream>>>(bsum, nb, offs, N, E);
    k_scanwrite<<<nb, 256, 0, stream>>>(deg, bsum, offs, cursor, N);
    k_scatter<<<eb, 256, 0, stream>>>(src, dst, cursor, srcs, E);

    // --- h0 = emb[x] ---
    k_gather<<<(N * DV + 255) / 256, 256, 0, stream>>>(x, emb, A, N);

    int mb   = (N + 63) / 64;
    int aggb = (N + 3) / 4;   // 4 waves (nodes) per 256-thread block

    // layer 1: A -> B
    k_gemm<<<mb, 512, 0, stream>>>(A, Wr[0], bl[0], nullptr, 0, B, N);
    k_agg<<<aggb, 256, 0, stream>>>(A, offs, srcs, C, N);
    k_gemm<<<mb, 512, 0, stream>>>(C, Wl[0], nullptr, pa[0], 1, B, N);
    // layer 2: B -> A
    k_gemm<<<mb, 512, 0, stream>>>(B, Wr[1], bl[1], nullptr, 0, A, N);
    k_agg<<<aggb, 256, 0, stream>>>(B, offs, srcs, C, N);
    k_gemm<<<mb, 512, 0, stream>>>(C, Wl[1], nullptr, pa[1], 1, A, N);
    // layer 3: A -> B
    k_gemm<<<mb, 512, 0, stream>>>(A, Wr[2], bl[2], nullptr, 0, B, N);
    k_agg<<<aggb, 256, 0, stream>>>(A, offs, srcs, C, N);
    k_gemm<<<mb, 512, 0, stream>>>(C, Wl[2], nullptr, pa[2], 1, B, N);
    // output projection (in-place on d_out; BN=256 blocks own rows exclusively)
    k_gemm<<<mb, 512, 0, stream>>>(B, Wout, bout, nullptr, 0, (float*)d_out, N);
}

// Round 2
// 1554.343 us; speedup vs baseline: 2.1191x; 2.1191x over previous
//
#include <hip/hip_runtime.h>

#define D 256
typedef unsigned short u16;
using short8 = __attribute__((ext_vector_type(8))) short;
using f32x4  = __attribute__((ext_vector_type(4))) float;

__device__ __forceinline__ u16 f2bf(float f) {
    unsigned u = __float_as_uint(f);
    unsigned r = (u + 0x7FFFu + ((u >> 16) & 1u)) >> 16;
    return (u16)r;
}
__device__ __forceinline__ float bf2f(u16 v) {
    return __uint_as_float(((unsigned)v) << 16);
}

__device__ __forceinline__ void load_lds16(const u16* g, u16* l) {
    __builtin_amdgcn_global_load_lds(
        (const __attribute__((address_space(1))) void*)g,
        (__attribute__((address_space(3))) void*)l, 16, 0, 0);
}

// ---------------- CSR build ----------------

__global__ void k_hist(const int* __restrict__ dst, int* __restrict__ deg, int E) {
    int e = blockIdx.x * blockDim.x + threadIdx.x;
    if (e < E) atomicAdd(&deg[dst[e]], 1);
}

__global__ void k_blocksum(const int* __restrict__ deg, int* __restrict__ bsum, int n) {
    __shared__ int s[256];
    int b = blockIdx.x, t = threadIdx.x;
    int base = b * 1024;
    int v = 0;
    for (int i = t; i < 1024; i += 256) {
        int idx = base + i;
        if (idx < n) v += deg[idx];
    }
    s[t] = v;
    __syncthreads();
    for (int off = 128; off > 0; off >>= 1) {
        if (t < off) s[t] += s[t + off];
        __syncthreads();
    }
    if (t == 0) bsum[b] = s[0];
}

__global__ void k_scanbsum(int* bsum, int nb, int* offs, int n, int total) {
    if (threadIdx.x == 0 && blockIdx.x == 0) {
        int run = 0;
        for (int i = 0; i < nb; i++) { int v = bsum[i]; bsum[i] = run; run += v; }
        offs[n] = total;
    }
}

__global__ void k_scanwrite(const int* __restrict__ deg, const int* __restrict__ bsum,
                            int* __restrict__ offs, int* __restrict__ cursor, int n) {
    __shared__ int s[256];
    int b = blockIdx.x, t = threadIdx.x;
    int base = b * 1024 + t * 4;
    int v[4];
    int sum = 0;
    #pragma unroll
    for (int j = 0; j < 4; j++) {
        int idx = base + j;
        v[j] = (idx < n) ? deg[idx] : 0;
        sum += v[j];
    }
    s[t] = sum;
    __syncthreads();
    for (int off = 1; off < 256; off <<= 1) {
        int xv = (t >= off) ? s[t - off] : 0;
        __syncthreads();
        s[t] += xv;
        __syncthreads();
    }
    int excl = s[t] - sum + bsum[b];
    #pragma unroll
    for (int j = 0; j < 4; j++) {
        int idx = base + j;
        if (idx < n) { offs[idx] = excl; cursor[idx] = excl; excl += v[j]; }
    }
}

__global__ void k_scatter(const int* __restrict__ src, const int* __restrict__ dst,
                          int* __restrict__ cursor, int* __restrict__ srcs, int E) {
    int e = blockIdx.x * blockDim.x + threadIdx.x;
    if (e < E) {
        int d = dst[e];
        int p = atomicAdd(&cursor[d], 1);
        srcs[p] = src[e];
    }
}

// ---------------- embedding gather -> bf16 ----------------

__global__ void k_gather_bf(const int* __restrict__ x, const float* __restrict__ emb,
                            u16* __restrict__ h, int N) {
    int idx = blockIdx.x * blockDim.x + threadIdx.x;
    if (idx >= N * 64) return;
    int node = idx >> 6, c = idx & 63;
    int s = x[node];
    float4 v = ((const float4*)emb)[(size_t)s * 64 + c];
    ushort4 o;
    o.x = f2bf(v.x); o.y = f2bf(v.y); o.z = f2bf(v.z); o.w = f2bf(v.w);
    ((ushort4*)h)[(size_t)node * 64 + c] = o;
}

// ---------------- weight fp32 -> bf16 (7 matrices of 256x256) ----------------

__global__ void k_cvtw(const float* w0, const float* w1, const float* w2,
                       const float* w3, const float* w4, const float* w5,
                       const float* w6, u16* __restrict__ out) {
    int idx = blockIdx.x * blockDim.x + threadIdx.x;
    if (idx >= 7 * 65536) return;
    int m = idx >> 16, off = idx & 65535;
    const float* w = w0;
    if (m == 1) w = w1; else if (m == 2) w = w2; else if (m == 3) w = w3;
    else if (m == 4) w = w4; else if (m == 5) w = w5; else if (m == 6) w = w6;
    out[idx] = f2bf(w[off]);
}

// ---------------- mean aggregation (bf16 rows, wave per node) ----------------

__global__ void k_agg_bf(const u16* __restrict__ h, const int* __restrict__ offs,
                         const int* __restrict__ srcs, u16* __restrict__ out, int N) {
    int wid = (blockIdx.x * blockDim.x + threadIdx.x) >> 6;
    int lane = threadIdx.x & 63;
    if (wid >= N) return;
    int beg = offs[wid], end = offs[wid + 1];
    int c = lane * 4;
    float a0 = 0.f, a1 = 0.f, a2 = 0.f, a3 = 0.f;
    int e = beg;
    for (; e + 3 < end; e += 4) {
        int j0 = srcs[e], j1 = srcs[e + 1], j2 = srcs[e + 2], j3 = srcs[e + 3];
        ushort4 v0 = *(const ushort4*)&h[(size_t)j0 * D + c];
        ushort4 v1 = *(const ushort4*)&h[(size_t)j1 * D + c];
        ushort4 v2 = *(const ushort4*)&h[(size_t)j2 * D + c];
        ushort4 v3 = *(const ushort4*)&h[(size_t)j3 * D + c];
        a0 += (bf2f(v0.x) + bf2f(v1.x)) + (bf2f(v2.x) + bf2f(v3.x));
        a1 += (bf2f(v0.y) + bf2f(v1.y)) + (bf2f(v2.y) + bf2f(v3.y));
        a2 += (bf2f(v0.z) + bf2f(v1.z)) + (bf2f(v2.z) + bf2f(v3.z));
        a3 += (bf2f(v0.w) + bf2f(v1.w)) + (bf2f(v2.w) + bf2f(v3.w));
    }
    for (; e < end; ++e) {
        int j = srcs[e];
        ushort4 v = *(const ushort4*)&h[(size_t)j * D + c];
        a0 += bf2f(v.x); a1 += bf2f(v.y); a2 += bf2f(v.z); a3 += bf2f(v.w);
    }
    int dg = end - beg;
    float inv = 1.0f / (float)(dg < 1 ? 1 : dg);
    ushort4 o;
    o.x = f2bf(a0 * inv); o.y = f2bf(a1 * inv); o.z = f2bf(a2 * inv); o.w = f2bf(a3 * inv);
    *(ushort4*)&out[(size_t)wid * D + c] = o;
}

// ---------------- fused MFMA GEMM ----------------
// out[M,256] = epi( sum_p Ap[M,256] @ Wp[256,256]^T + bias ), bf16 inputs, fp32 acc.
// BM=128, BN=128, BK=32; 256 thr = 4 waves in 2x2; 16x16x32 bf16 MFMA.

__global__ __launch_bounds__(256)
void k_fgemm(const u16* __restrict__ A0, const u16* __restrict__ W0,
             const u16* __restrict__ A1, const u16* __restrict__ W1,
             int npairs,
             const float* __restrict__ bias, const float* __restrict__ prelu_a,
             void* __restrict__ outp, int out_bf16, int M) {
    __shared__ u16 As[128 * 32];
    __shared__ u16 Bs[128 * 32];
    int t = threadIdx.x;
    int wave = t >> 6, lane = t & 63;
    int r = lane & 15, quad = lane >> 4;
    int wm = (wave & 1) * 64, wn = (wave >> 1) * 64;
    int m0 = blockIdx.x * 128;
    int n0 = blockIdx.y * 128;

    f32x4 acc[4][4];
    #pragma unroll
    for (int i = 0; i < 4; i++)
        #pragma unroll
        for (int j = 0; j < 4; j++)
            acc[i][j] = (f32x4){0.f, 0.f, 0.f, 0.f};

    // staging geometry: seg s (0..511) covers row s>>2, col-chunk (s&3)*8 (16B)
    int sA = t;            // segs t and t+256
    int rowA0 = sA >> 2, csA0 = (sA & 3) * 8;
    int sB = t + 256;
    int rowA1 = sB >> 2, csA1 = (sB & 3) * 8;
    u16* ldsA0 = &As[(size_t)(wave * 64) * 8];
    u16* ldsA1 = &As[(size_t)(256 + wave * 64) * 8];
    u16* ldsB0 = &Bs[(size_t)(wave * 64) * 8];
    u16* ldsB1 = &Bs[(size_t)(256 + wave * 64) * 8];

    for (int p = 0; p < npairs; ++p) {
        const u16* Ag = p ? A1 : A0;
        const u16* Wg = p ? W1 : W0;
        for (int kt = 0; kt < 8; ++kt) {
            int k0 = kt * 32;
            __syncthreads();
            load_lds16(Ag + (size_t)(m0 + rowA0) * D + k0 + csA0, ldsA0);
            load_lds16(Ag + (size_t)(m0 + rowA1) * D + k0 + csA1, ldsA1);
            load_lds16(Wg + (size_t)(n0 + rowA0) * D + k0 + csA0, ldsB0);
            load_lds16(Wg + (size_t)(n0 + rowA1) * D + k0 + csA1, ldsB1);
            __syncthreads();

            short8 a[4], b[4];
            #pragma unroll
            for (int mt = 0; mt < 4; mt++)
                a[mt] = *(const short8*)&As[(wm + mt * 16 + r) * 32 + quad * 8];
            #pragma unroll
            for (int nt = 0; nt < 4; nt++)
                b[nt] = *(const short8*)&Bs[(wn + nt * 16 + r) * 32 + quad * 8];
            #pragma unroll
            for (int mt = 0; mt < 4; mt++)
                #pragma unroll
                for (int nt = 0; nt < 4; nt++)
                    acc[mt][nt] = __builtin_amdgcn_mfma_f32_16x16x32_bf16(
                        a[mt], b[nt], acc[mt][nt], 0, 0, 0);
        }
    }

    float pa = prelu_a ? *prelu_a : 0.f;
    int dop = prelu_a != nullptr;
    #pragma unroll
    for (int nt = 0; nt < 4; nt++) {
        int col = n0 + wn + nt * 16 + r;
        float bv = bias ? bias[col] : 0.f;
        #pragma unroll
        for (int mt = 0; mt < 4; mt++) {
            #pragma unroll
            for (int i = 0; i < 4; i++) {
                int row = m0 + wm + mt * 16 + quad * 4 + i;
                if (row < M) {
                    float v = acc[mt][nt][i] + bv;
                    if (dop) v = (v >= 0.f) ? v : pa * v;
                    if (out_bf16)
                        ((u16*)outp)[(size_t)row * D + col] = f2bf(v);
                    else
                        ((float*)outp)[(size_t)row * D + col] = v;
                }
            }
        }
    }
}

// ---------------- launcher ----------------

extern "C" void kernel_launch(void* const* d_in, const int* in_sizes, int n_in,
                              void* d_out, int out_size, void* d_ws, size_t ws_size,
                              hipStream_t stream) {
    const int*   x    = (const int*)d_in[0];
    const int*   ei   = (const int*)d_in[1];
    const float* emb  = (const float*)d_in[3];
    const float* Wl[3] = {(const float*)d_in[4],  (const float*)d_in[8],  (const float*)d_in[12]};
    const float* bl[3] = {(const float*)d_in[5],  (const float*)d_in[9],  (const float*)d_in[13]};
    const float* Wr[3] = {(const float*)d_in[6],  (const float*)d_in[10], (const float*)d_in[14]};
    const float* pa[3] = {(const float*)d_in[7],  (const float*)d_in[11], (const float*)d_in[15]};
    const float* Wout = (const float*)d_in[16];
    const float* bout = (const float*)d_in[17];

    int N = in_sizes[0];
    int E = in_sizes[1] / 2;
    const int* src = ei;
    const int* dst = ei + E;

    char* ws = (char*)d_ws;
    size_t off = 0;
    auto walloc = [&](size_t bytes) -> void* {
        void* p = ws + off;
        off += (bytes + 255) & ~(size_t)255;
        return p;
    };
    // order matters: tile staging over-reads up to ~49 KB past row M-1;
    // keep every activation buffer followed by more ws.
    u16* hA   = (u16*)walloc((size_t)N * D * sizeof(u16));
    u16* hB   = (u16*)walloc((size_t)N * D * sizeof(u16));
    u16* mean = (u16*)walloc((size_t)N * D * sizeof(u16));
    u16* wbf  = (u16*)walloc((size_t)7 * 65536 * sizeof(u16));
    int* deg    = (int*)walloc((size_t)N * sizeof(int));
    int* offs   = (int*)walloc((size_t)(N + 1) * sizeof(int));
    int* cursor = (int*)walloc((size_t)N * sizeof(int));
    int* bsum   = (int*)walloc(4096);
    int* srcs   = (int*)walloc((size_t)E * sizeof(int));

    u16* Wlb[3] = {wbf + 0 * 65536, wbf + 2 * 65536, wbf + 4 * 65536};
    u16* Wrb[3] = {wbf + 1 * 65536, wbf + 3 * 65536, wbf + 5 * 65536};
    u16* Woutb  = wbf + 6 * 65536;

    // --- weights -> bf16 ---
    k_cvtw<<<(7 * 65536 + 255) / 256, 256, 0, stream>>>(
        Wl[0], Wr[0], Wl[1], Wr[1], Wl[2], Wr[2], Wout, wbf);

    // --- CSR build ---
    hipMemsetAsync(deg, 0, (size_t)N * sizeof(int), stream);
    int eb = (E + 255) / 256;
    int nb = (N + 1023) / 1024;
    k_hist<<<eb, 256, 0, stream>>>(dst, deg, E);
    k_blocksum<<<nb, 256, 0, stream>>>(deg, bsum, N);
    k_scanbsum<<<1, 64, 0, stream>>>(bsum, nb, offs, N, E);
    k_scanwrite<<<nb, 256, 0, stream>>>(deg, bsum, offs, cursor, N);
    k_scatter<<<eb, 256, 0, stream>>>(src, dst, cursor, srcs, E);

    // --- h0 = bf16(emb[x]) ---
    k_gather_bf<<<(N * 64 + 255) / 256, 256, 0, stream>>>(x, emb, hA, N);

    int mb   = (N + 127) / 128;
    dim3 ggrid(mb, 2);
    int aggb = (N + 3) / 4;

    // layer 1: hA -> hB
    k_agg_bf<<<aggb, 256, 0, stream>>>(hA, offs, srcs, mean, N);
    k_fgemm<<<ggrid, 256, 0, stream>>>(mean, Wlb[0], hA, Wrb[0], 2, bl[0], pa[0], hB, 1, N);
    // layer 2: hB -> hA
    k_agg_bf<<<aggb, 256, 0, stream>>>(hB, offs, srcs, mean, N);
    k_fgemm<<<ggrid, 256, 0, stream>>>(mean, Wlb[1], hB, Wrb[1], 2, bl[1], pa[1], hA, 1, N);
    // layer 3: hA -> hB
    k_agg_bf<<<aggb, 256, 0, stream>>>(hA, offs, srcs, mean, N);
    k_fgemm<<<ggrid, 256, 0, stream>>>(mean, Wlb[2], hA, Wrb[2], 2, bl[2], pa[2], hB, 1, N);
    // output projection -> fp32 d_out
    k_fgemm<<<ggrid, 256, 0, stream>>>(hB, Woutb, nullptr, nullptr, 1, bout, nullptr, d_out, 0, N);
}

// Round 3
// 1437.385 us; speedup vs baseline: 2.2915x; 1.0814x over previous
//
#include <hip/hip_runtime.h>

#define D 256
typedef unsigned short u16;
using short8  = __attribute__((ext_vector_type(8))) short;
using ushort8 = __attribute__((ext_vector_type(8))) unsigned short;
using f32x4   = __attribute__((ext_vector_type(4))) float;

__device__ __forceinline__ u16 f2bf(float f) {
    unsigned u = __float_as_uint(f);
    unsigned r = (u + 0x7FFFu + ((u >> 16) & 1u)) >> 16;
    return (u16)r;
}
__device__ __forceinline__ float bf2f(u16 v) {
    return __uint_as_float(((unsigned)v) << 16);
}

__device__ __forceinline__ void load_lds16(const u16* g, u16* l) {
    __builtin_amdgcn_global_load_lds(
        (const __attribute__((address_space(1))) void*)g,
        (__attribute__((address_space(3))) void*)l, 16, 0, 0);
}

// ---------------- CSR build ----------------

__global__ void k_hist(const int* __restrict__ dst, int* __restrict__ deg, int E) {
    int e = blockIdx.x * blockDim.x + threadIdx.x;
    if (e < E) atomicAdd(&deg[dst[e]], 1);
}

__global__ void k_blocksum(const int* __restrict__ deg, int* __restrict__ bsum, int n) {
    __shared__ int s[256];
    int b = blockIdx.x, t = threadIdx.x;
    int base = b * 1024;
    int v = 0;
    for (int i = t; i < 1024; i += 256) {
        int idx = base + i;
        if (idx < n) v += deg[idx];
    }
    s[t] = v;
    __syncthreads();
    for (int off = 128; off > 0; off >>= 1) {
        if (t < off) s[t] += s[t + off];
        __syncthreads();
    }
    if (t == 0) bsum[b] = s[0];
}

__global__ void k_scanbsum(int* bsum, int nb, int* offs, int n, int total) {
    if (threadIdx.x == 0 && blockIdx.x == 0) {
        int run = 0;
        for (int i = 0; i < nb; i++) { int v = bsum[i]; bsum[i] = run; run += v; }
        offs[n] = total;
    }
}

__global__ void k_scanwrite(const int* __restrict__ deg, const int* __restrict__ bsum,
                            int* __restrict__ offs, int* __restrict__ cursor, int n) {
    __shared__ int s[256];
    int b = blockIdx.x, t = threadIdx.x;
    int base = b * 1024 + t * 4;
    int v[4];
    int sum = 0;
    #pragma unroll
    for (int j = 0; j < 4; j++) {
        int idx = base + j;
        v[j] = (idx < n) ? deg[idx] : 0;
        sum += v[j];
    }
    s[t] = sum;
    __syncthreads();
    for (int off = 1; off < 256; off <<= 1) {
        int xv = (t >= off) ? s[t - off] : 0;
        __syncthreads();
        s[t] += xv;
        __syncthreads();
    }
    int excl = s[t] - sum + bsum[b];
    #pragma unroll
    for (int j = 0; j < 4; j++) {
        int idx = base + j;
        if (idx < n) { offs[idx] = excl; cursor[idx] = excl; excl += v[j]; }
    }
}

// dst-range-filtered scatter: active srcs region stays L2-resident per pass
__global__ void k_scatter_rng(const int* __restrict__ src, const int* __restrict__ dst,
                              int* __restrict__ cursor, int* __restrict__ srcs,
                              int E, int lo, int hi) {
    int e = blockIdx.x * blockDim.x + threadIdx.x;
    if (e < E) {
        int d = dst[e];
        if (d >= lo && d < hi) {
            int p = atomicAdd(&cursor[d], 1);
            srcs[p] = src[e];
        }
    }
}

// ---------------- embedding gather -> bf16 ----------------

__global__ void k_gather_bf(const int* __restrict__ x, const float* __restrict__ emb,
                            u16* __restrict__ h, int N) {
    int idx = blockIdx.x * blockDim.x + threadIdx.x;
    if (idx >= N * 64) return;
    int node = idx >> 6, c = idx & 63;
    int s = x[node];
    float4 v = ((const float4*)emb)[(size_t)s * 64 + c];
    ushort4 o;
    o.x = f2bf(v.x); o.y = f2bf(v.y); o.z = f2bf(v.z); o.w = f2bf(v.w);
    ((ushort4*)h)[(size_t)node * 64 + c] = o;
}

// ---------------- weight fp32 -> bf16 ----------------

__global__ void k_cvtw(const float* w0, const float* w1, const float* w2,
                       const float* w3, const float* w4, const float* w5,
                       const float* w6, u16* __restrict__ out) {
    int idx = blockIdx.x * blockDim.x + threadIdx.x;
    if (idx >= 7 * 65536) return;
    int m = idx >> 16, off = idx & 65535;
    const float* w = w0;
    if (m == 1) w = w1; else if (m == 2) w = w2; else if (m == 3) w = w3;
    else if (m == 4) w = w4; else if (m == 5) w = w5; else if (m == 6) w = w6;
    out[idx] = f2bf(w[off]);
}

// ---------------- mean aggregation (wave/node, 16B loads, 2 edges parallel) ----

__global__ void k_agg_bf(const u16* __restrict__ h, const int* __restrict__ offs,
                         const int* __restrict__ srcs, u16* __restrict__ out, int N) {
    int wid = (blockIdx.x * blockDim.x + threadIdx.x) >> 6;
    int lane = threadIdx.x & 63;
    if (wid >= N) return;
    int beg = offs[wid], end = offs[wid + 1];
    int half = lane >> 5;          // which edge of the pair
    int cl = lane & 31;            // 16B col chunk within the 512B row
    float acc[8];
    #pragma unroll
    for (int i = 0; i < 8; i++) acc[i] = 0.f;
    int e = beg + half;
    for (; e + 6 < end; e += 8) {
        int j0 = srcs[e], j1 = srcs[e + 2], j2 = srcs[e + 4], j3 = srcs[e + 6];
        ushort8 v0 = *(const ushort8*)&h[(size_t)j0 * D + cl * 8];
        ushort8 v1 = *(const ushort8*)&h[(size_t)j1 * D + cl * 8];
        ushort8 v2 = *(const ushort8*)&h[(size_t)j2 * D + cl * 8];
        ushort8 v3 = *(const ushort8*)&h[(size_t)j3 * D + cl * 8];
        #pragma unroll
        for (int i = 0; i < 8; i++)
            acc[i] += (bf2f(v0[i]) + bf2f(v1[i])) + (bf2f(v2[i]) + bf2f(v3[i]));
    }
    for (; e < end; e += 2) {
        int j = srcs[e];
        ushort8 v = *(const ushort8*)&h[(size_t)j * D + cl * 8];
        #pragma unroll
        for (int i = 0; i < 8; i++) acc[i] += bf2f(v[i]);
    }
    #pragma unroll
    for (int i = 0; i < 8; i++) acc[i] += __shfl_xor(acc[i], 32);
    if (half == 0) {
        int dg = end - beg;
        float inv = 1.0f / (float)(dg < 1 ? 1 : dg);
        ushort8 o;
        #pragma unroll
        for (int i = 0; i < 8; i++) o[i] = f2bf(acc[i] * inv);
        *(ushort8*)&out[(size_t)wid * D + cl * 8] = o;
    }
}

// ---------------- fused MFMA GEMM ----------------
// out[M,256] = epi( sum_p Ap[M,256] @ Wp[256,256]^T + bias ), bf16 in, fp32 acc.
// BM=128, BN=256 (full width), BK=32; 512 thr = 8 waves (2x4); 16x16x32 bf16.

__global__ __launch_bounds__(512)
void k_fgemm(const u16* __restrict__ A0, const u16* __restrict__ W0,
             const u16* __restrict__ A1, const u16* __restrict__ W1,
             int npairs,
             const float* __restrict__ bias, const float* __restrict__ prelu_a,
             void* __restrict__ outp, int out_bf16, int M) {
    __shared__ u16 As[128 * 32];
    __shared__ u16 Bs[256 * 32];
    int t = threadIdx.x;
    int wave = t >> 6, lane = t & 63;
    int r = lane & 15, quad = lane >> 4;
    int wm = (wave & 1) * 64;       // 0 / 64
    int wn = (wave >> 1) * 64;      // 0 / 64 / 128 / 192
    int m0 = blockIdx.x * 128;

    f32x4 acc[4][4];
    #pragma unroll
    for (int i = 0; i < 4; i++)
        #pragma unroll
        for (int j = 0; j < 4; j++)
            acc[i][j] = (f32x4){0.f, 0.f, 0.f, 0.f};

    // staging: seg s covers (row = s>>2, 16B chunk = s&3); lane-contiguous per wave
    int rowA  = t >> 2,           colA  = (t & 3) * 8;          // A segs 0..511
    int rowB0 = t >> 2,           colB0 = (t & 3) * 8;          // B rows 0..127
    int rowB1 = (t + 512) >> 2,   colB1 = (t & 3) * 8;          // B rows 128..255
    u16* ldsA  = &As[wave * 512];
    u16* ldsB0 = &Bs[wave * 512];
    u16* ldsB1 = &Bs[4096 + wave * 512];

    for (int p = 0; p < npairs; ++p) {
        const u16* Ag = p ? A1 : A0;
        const u16* Wg = p ? W1 : W0;
        for (int kt = 0; kt < 8; ++kt) {
            int k0 = kt * 32;
            __syncthreads();
            load_lds16(Ag + (size_t)(m0 + rowA) * D + k0 + colA, ldsA);
            load_lds16(Wg + (size_t)rowB0 * D + k0 + colB0, ldsB0);
            load_lds16(Wg + (size_t)rowB1 * D + k0 + colB1, ldsB1);
            __syncthreads();

            short8 a[4], b[4];
            #pragma unroll
            for (int mt = 0; mt < 4; mt++)
                a[mt] = *(const short8*)&As[(wm + mt * 16 + r) * 32 + quad * 8];
            #pragma unroll
            for (int nt = 0; nt < 4; nt++)
                b[nt] = *(const short8*)&Bs[(wn + nt * 16 + r) * 32 + quad * 8];
            #pragma unroll
            for (int mt = 0; mt < 4; mt++)
                #pragma unroll
                for (int nt = 0; nt < 4; nt++)
                    acc[mt][nt] = __builtin_amdgcn_mfma_f32_16x16x32_bf16(
                        a[mt], b[nt], acc[mt][nt], 0, 0, 0);
        }
    }

    float pa = prelu_a ? *prelu_a : 0.f;
    int dop = prelu_a != nullptr;
    #pragma unroll
    for (int nt = 0; nt < 4; nt++) {
        int col = wn + nt * 16 + r;
        float bv = bias ? bias[col] : 0.f;
        #pragma unroll
        for (int mt = 0; mt < 4; mt++) {
            #pragma unroll
            for (int i = 0; i < 4; i++) {
                int row = m0 + wm + mt * 16 + quad * 4 + i;
                if (row < M) {
                    float v = acc[mt][nt][i] + bv;
                    if (dop) v = (v >= 0.f) ? v : pa * v;
                    if (out_bf16)
                        ((u16*)outp)[(size_t)row * D + col] = f2bf(v);
                    else
                        ((float*)outp)[(size_t)row * D + col] = v;
                }
            }
        }
    }
}

// ---------------- launcher ----------------

extern "C" void kernel_launch(void* const* d_in, const int* in_sizes, int n_in,
                              void* d_out, int out_size, void* d_ws, size_t ws_size,
                              hipStream_t stream) {
    const int*   x    = (const int*)d_in[0];
    const int*   ei   = (const int*)d_in[1];
    const float* emb  = (const float*)d_in[3];
    const float* Wl[3] = {(const float*)d_in[4],  (const float*)d_in[8],  (const float*)d_in[12]};
    const float* bl[3] = {(const float*)d_in[5],  (const float*)d_in[9],  (const float*)d_in[13]};
    const float* Wr[3] = {(const float*)d_in[6],  (const float*)d_in[10], (const float*)d_in[14]};
    const float* pa[3] = {(const float*)d_in[7],  (const float*)d_in[11], (const float*)d_in[15]};
    const float* Wout = (const float*)d_in[16];
    const float* bout = (const float*)d_in[17];

    int N = in_sizes[0];
    int E = in_sizes[1] / 2;
    const int* src = ei;
    const int* dst = ei + E;

    char* ws = (char*)d_ws;
    size_t off = 0;
    auto walloc = [&](size_t bytes) -> void* {
        void* p = ws + off;
        off += (bytes + 255) & ~(size_t)255;
        return p;
    };
    // tile staging over-reads up to ~49 KB past row M-1: keep activations mid-ws
    u16* hA   = (u16*)walloc((size_t)N * D * sizeof(u16));
    u16* hB   = (u16*)walloc((size_t)N * D * sizeof(u16));
    u16* mean = (u16*)walloc((size_t)N * D * sizeof(u16));
    u16* wbf  = (u16*)walloc((size_t)7 * 65536 * sizeof(u16));
    int* deg    = (int*)walloc((size_t)N * sizeof(int));
    int* offs   = (int*)walloc((size_t)(N + 1) * sizeof(int));
    int* cursor = (int*)walloc((size_t)N * sizeof(int));
    int* bsum   = (int*)walloc(4096);
    int* srcs   = (int*)walloc((size_t)E * sizeof(int));

    u16* Wlb[3] = {wbf + 0 * 65536, wbf + 2 * 65536, wbf + 4 * 65536};
    u16* Wrb[3] = {wbf + 1 * 65536, wbf + 3 * 65536, wbf + 5 * 65536};
    u16* Woutb  = wbf + 6 * 65536;

    // --- weights -> bf16 ---
    k_cvtw<<<(7 * 65536 + 255) / 256, 256, 0, stream>>>(
        Wl[0], Wr[0], Wl[1], Wr[1], Wl[2], Wr[2], Wout, wbf);

    // --- CSR build ---
    hipMemsetAsync(deg, 0, (size_t)N * sizeof(int), stream);
    int eb = (E + 255) / 256;
    int nb = (N + 1023) / 1024;
    k_hist<<<eb, 256, 0, stream>>>(dst, deg, E);
    k_blocksum<<<nb, 256, 0, stream>>>(deg, bsum, N);
    k_scanbsum<<<1, 64, 0, stream>>>(bsum, nb, offs, N, E);
    k_scanwrite<<<nb, 256, 0, stream>>>(deg, bsum, offs, cursor, N);
    const int NCH = 8;
    for (int c = 0; c < NCH; c++) {
        int lo = (int)((size_t)N * c / NCH);
        int hi = (int)((size_t)N * (c + 1) / NCH);
        k_scatter_rng<<<eb, 256, 0, stream>>>(src, dst, cursor, srcs, E, lo, hi);
    }

    // --- h0 = bf16(emb[x]) ---
    k_gather_bf<<<(N * 64 + 255) / 256, 256, 0, stream>>>(x, emb, hA, N);

    int mb   = (N + 127) / 128;
    int aggb = (N + 3) / 4;

    // layer 1: hA -> hB
    k_agg_bf<<<aggb, 256, 0, stream>>>(hA, offs, srcs, mean, N);
    k_fgemm<<<mb, 512, 0, stream>>>(mean, Wlb[0], hA, Wrb[0], 2, bl[0], pa[0], hB, 1, N);
    // layer 2: hB -> hA
    k_agg_bf<<<aggb, 256, 0, stream>>>(hB, offs, srcs, mean, N);
    k_fgemm<<<mb, 512, 0, stream>>>(mean, Wlb[1], hB, Wrb[1], 2, bl[1], pa[1], hA, 1, N);
    // layer 3: hA -> hB
    k_agg_bf<<<aggb, 256, 0, stream>>>(hA, offs, srcs, mean, N);
    k_fgemm<<<mb, 512, 0, stream>>>(mean, Wlb[2], hA, Wrb[2], 2, bl[2], pa[2], hB, 1, N);
    // output projection -> fp32 d_out
    k_fgemm<<<mb, 512, 0, stream>>>(hB, Woutb, hB, Woutb, 1, bout, nullptr, d_out, 0, N);
}